// Round 17
// baseline (195.047 us; speedup 1.0000x reference)
//
#include <hip/hip_runtime.h>
#include <hip/hip_bf16.h>

#define EMB 64

typedef __attribute__((ext_vector_type(8))) short short8;
typedef __attribute__((ext_vector_type(8))) __bf16 bf16x8;
typedef __attribute__((ext_vector_type(4))) float f32x4;

__device__ inline f32x4 mfma16x16x32(short8 a, short8 b, f32x4 c) {
  return __builtin_amdgcn_mfma_f32_16x16x32_bf16(
      __builtin_bit_cast(bf16x8, a), __builtin_bit_cast(bf16x8, b), c, 0, 0, 0);
}

// Raw v_exp_f32 (2^x). OCML exp2f/__expf are multi-instr expansions (r2-r4).
#define EXP2_HW __builtin_amdgcn_exp2f
#define C5LOG2E 7.213475204444817f  // 5 * log2(e)

// prep: 512 blocks x 16 rows, 16-lane-group float4 layout (r11-proven).
// Also clears the global dedup bitmap and done-counter (stream order safe).
__global__ __launch_bounds__(256) void prep_kernel(
    const int* __restrict__ user, const int* __restrict__ pos,
    const float* __restrict__ uw, const float* __restrict__ iw,
    __hip_bfloat16* __restrict__ u_bf, __hip_bfloat16* __restrict__ p_bf,
    float* __restrict__ up_p, unsigned int* __restrict__ bitmap,
    unsigned int* __restrict__ done_cnt)
{
  const int tid  = threadIdx.x;
  const int wave = tid >> 6;
  const int lane = tid & 63;
  const int e    = lane & 15;
  const int row  = blockIdx.x * 16 + wave * 4 + (lane >> 4);

  {
    const int ci = blockIdx.x * 256 + tid;
    if (ci < 6250) bitmap[ci] = 0u;
    if (ci == 6250) *done_cnt = 0u;
  }

  const int uidx = user[row];
  const int pidx = pos[row];
  const float4 uv = *reinterpret_cast<const float4*>(&uw[(size_t)uidx * EMB + e * 4]);
  const float4 pv = *reinterpret_cast<const float4*>(&iw[(size_t)pidx * EMB + e * 4]);

  float us = uv.x*uv.x + uv.y*uv.y + uv.z*uv.z + uv.w*uv.w;
  float ps = pv.x*pv.x + pv.y*pv.y + pv.z*pv.z + pv.w*pv.w;
  #pragma unroll
  for (int off = 1; off < 16; off <<= 1) {
    us += __shfl_xor(us, off);
    ps += __shfl_xor(ps, off);
  }
  const float ur = 1.0f / fmaxf(sqrtf(us), 1e-12f);
  const float pr = 1.0f / fmaxf(sqrtf(ps), 1e-12f);
  const float4 un = make_float4(uv.x*ur, uv.y*ur, uv.z*ur, uv.w*ur);
  const float4 pn = make_float4(pv.x*pr, pv.y*pr, pv.z*pr, pv.w*pr);

  ushort4 ub, pb;
  ub.x = __bfloat16_as_ushort(__float2bfloat16(un.x));
  ub.y = __bfloat16_as_ushort(__float2bfloat16(un.y));
  ub.z = __bfloat16_as_ushort(__float2bfloat16(un.z));
  ub.w = __bfloat16_as_ushort(__float2bfloat16(un.w));
  pb.x = __bfloat16_as_ushort(__float2bfloat16(pn.x));
  pb.y = __bfloat16_as_ushort(__float2bfloat16(pn.y));
  pb.z = __bfloat16_as_ushort(__float2bfloat16(pn.z));
  pb.w = __bfloat16_as_ushort(__float2bfloat16(pn.w));
  *reinterpret_cast<ushort4*>(&u_bf[(size_t)row * EMB + e * 4]) = ub;
  *reinterpret_cast<ushort4*>(&p_bf[(size_t)row * EMB + e * 4]) = pb;

  float ip = un.x*pn.x + un.y*pn.y + un.z*pn.z + un.w*pn.w;
  #pragma unroll
  for (int off = 1; off < 16; off <<= 1) ip += __shfl_xor(ip, off);

  float upv = 0.0f;
  if (e == 0) {
    const float t = ip * C5LOG2E;
    upv = logf(EXP2_HW(t) + EXP2_HW(ip * t));  // log(exp(ip/T)+exp(ip^2/T))
  }
  upv += __shfl_xor(upv, 16);
  upv += __shfl_xor(upv, 32);

  __shared__ float sred[4];
  if (lane == 0) sred[wave] = upv;
  __syncthreads();
  if (tid == 0)
    up_p[blockIdx.x] = (sred[0] + sred[1]) + (sred[2] + sred[3]);
}

// 2048 blocks = 64 row-strips x 32 col-groups x 2 tiles; 64x32 half-steps.
// OCCUPANCY BY GRID: r16's 512 blocks supplied only 2 waves/SIMD (74us);
// 2048 blocks x 4 waves / 256 CU = 32 waves/CU = 8 waves/SIMD — the HW cap,
// and exactly what the 60-VGPR shape allows (8x60=480<=512). Fused
// last-block-done tail does bitmap popcount + final reduce (no finalize
// dispatch).
__global__ __launch_bounds__(256) void gemm_kernel(
    const __hip_bfloat16* __restrict__ U, const __hip_bfloat16* __restrict__ P,
    const int* __restrict__ user, const int* __restrict__ pos,
    const float* __restrict__ up_p, float* __restrict__ dn_p,
    unsigned int* __restrict__ bitmap, unsigned int* __restrict__ done_cnt,
    float* __restrict__ out)
{
  const int tid  = threadIdx.x;
  const int blk  = blockIdx.x;
  const int by   = blk >> 5;           // [0,64)
  const int bx0  = (blk & 31) << 1;    // 2 tiles -> 64 col-tiles
  const int wave = tid >> 6;
  const int lane = tid & 63;
  const int r0   = by * 128 + (wave >> 1) * 64;
  const int lrow = lane & 15;
  const int lk   = (lane >> 4) * 8;

  // Dedup scatter (rows blk*256 .. +255), overlaps with A-load latency.
  if (blk < 32) {
    const int i = blk * 256 + tid;
    const int u = user[i];
    const int p = pos[i];
    atomicOr(&bitmap[u >> 5], 1u << (u & 31));
    atomicOr(&bitmap[3125 + (p >> 5)], 1u << (p & 31));
  }

  short8 a[4][2];
  #pragma unroll
  for (int i = 0; i < 4; ++i)
    #pragma unroll
    for (int kk = 0; kk < 2; ++kk)
      a[i][kk] = *reinterpret_cast<const short8*>(
          &U[(size_t)(r0 + i * 16 + lrow) * EMB + kk * 32 + lk]);

  float s0 = 0.0f, s1 = 0.0f, s2 = 0.0f, s3 = 0.0f;

  #pragma unroll 1
  for (int s = 0; s < 4; ++s) {
    // step s: tile t = s>>1, half h = s&1 -> 64 rows x 32 cols
    const int c0 = (bx0 + (s >> 1)) * 128 + (wave & 1) * 64 + (s & 1) * 32;

    short8 b[2][2];
    #pragma unroll
    for (int j = 0; j < 2; ++j)
      #pragma unroll
      for (int kk = 0; kk < 2; ++kk)
        b[j][kk] = *reinterpret_cast<const short8*>(
            &P[(size_t)(c0 + j * 16 + lrow) * EMB + kk * 32 + lk]);

    f32x4 acc[4][2] = {};
    #pragma unroll
    for (int i = 0; i < 4; ++i)
      #pragma unroll
      for (int j = 0; j < 2; ++j) {
        acc[i][j] = mfma16x16x32(a[i][0], b[j][0], acc[i][j]);
        acc[i][j] = mfma16x16x32(a[i][1], b[j][1], acc[i][j]);
      }

    // exp(v/T)=2^(v*C); exp(v^2/T)=2^(v*(v*C)); |v|<=~1.
    #pragma unroll
    for (int i = 0; i < 4; ++i)
      #pragma unroll
      for (int j = 0; j < 2; ++j)
        #pragma unroll
        for (int r = 0; r < 4; ++r) {
          const float v  = acc[i][j][r];
          const float tt = v * C5LOG2E;
          if (j) { s2 += EXP2_HW(tt); s3 += EXP2_HW(v * tt); }
          else   { s0 += EXP2_HW(tt); s1 += EXP2_HW(v * tt); }
        }
  }

  float s = (s0 + s1) + (s2 + s3);
  #pragma unroll
  for (int off = 32; off; off >>= 1) s += __shfl_xor(s, off);

  __shared__ float sredf[4];
  __shared__ unsigned int is_last;
  if (lane == 0) sredf[wave] = s;
  __syncthreads();
  if (tid == 0)
    dn_p[blk] = (sredf[0] + sredf[1]) + (sredf[2] + sredf[3]);

  // ---- last-block-done: dedup popcount + final reduction ----
  __threadfence();                      // release dn_p + bitmap scatters
  if (tid == 0)
    is_last = (atomicAdd(done_cnt, 1u) == 2047u) ? 1u : 0u;
  __syncthreads();
  if (!is_last) return;
  __threadfence();                      // acquire all blocks' writes

  int uc = 0, ic = 0;
  for (int i = tid; i < 3125; i += 256) uc += __popc(bitmap[i]);
  for (int i = tid; i < 3125; i += 256) ic += __popc(bitmap[3125 + i]);
  float upv = 0.0f, dnv = 0.0f;
  for (int i = tid; i < 512; i += 256)  upv += up_p[i];
  for (int i = tid; i < 2048; i += 256) dnv += dn_p[i];

  #pragma unroll
  for (int off = 32; off; off >>= 1) {
    upv += __shfl_xor(upv, off);
    dnv += __shfl_xor(dnv, off);
    uc  += __shfl_xor(uc, off);
    ic  += __shfl_xor(ic, off);
  }

  __shared__ float ff[2][4];
  __shared__ int   gg[2][4];
  if (lane == 0) { ff[0][wave] = upv; ff[1][wave] = dnv; gg[0][wave] = uc; gg[1][wave] = ic; }
  __syncthreads();
  if (tid == 0) {
    const float usum = (ff[0][0] + ff[0][1]) + (ff[0][2] + ff[0][3]);
    const float dsum = (ff[1][0] + ff[1][1]) + (ff[1][2] + ff[1][3]);
    const int   nu   = gg[0][0] + gg[0][1] + gg[0][2] + gg[0][3];
    const int   ni   = gg[1][0] + gg[1][1] + gg[1][2] + gg[1][3];
    out[0] = -(usum / 8192.0f);
    out[1] = logf(dsum / ((float)nu * (float)ni));
  }
}

extern "C" void kernel_launch(void* const* d_in, const int* in_sizes, int n_in,
                              void* d_out, int out_size, void* d_ws, size_t ws_size,
                              hipStream_t stream) {
  const int*   user = (const int*)d_in[0];
  const int*   pos  = (const int*)d_in[1];
  // d_in[2] = negative (unused by the reference loss)
  const float* uw   = (const float*)d_in[3];
  const float* iw   = (const float*)d_in[4];
  float* out = (float*)d_out;

  char* ws = (char*)d_ws;
  __hip_bfloat16* u_bf = (__hip_bfloat16*)(ws);
  __hip_bfloat16* p_bf = (__hip_bfloat16*)(ws + (1u << 20));
  float* up_p = (float*)(ws + (2u << 20));               // 512
  float* dn_p = up_p + 512;                              // 2048
  unsigned int* bitmap   = (unsigned int*)(dn_p + 2048); // 6250 words (25 KB)
  unsigned int* done_cnt = bitmap + 6250;

  prep_kernel<<<512, 256, 0, stream>>>(user, pos, uw, iw, u_bf, p_bf,
                                       up_p, bitmap, done_cnt);
  gemm_kernel<<<2048, 256, 0, stream>>>(u_bf, p_bf, user, pos,
                                        up_p, dn_p, bitmap, done_cnt, out);
}

// Round 18
// 42.295 us; speedup vs baseline: 4.6116x; 4.6116x over previous
//
#include <hip/hip_runtime.h>
#include <hip/hip_bf16.h>

#define EMB 64

typedef __attribute__((ext_vector_type(8))) short short8;
typedef __attribute__((ext_vector_type(8))) __bf16 bf16x8;
typedef __attribute__((ext_vector_type(4))) float f32x4;

__device__ inline f32x4 mfma16x16x32(short8 a, short8 b, f32x4 c) {
  return __builtin_amdgcn_mfma_f32_16x16x32_bf16(
      __builtin_bit_cast(bf16x8, a), __builtin_bit_cast(bf16x8, b), c, 0, 0, 0);
}

// Raw v_exp_f32 (2^x). OCML exp2f/__expf are multi-instr expansions (r2-r4).
#define EXP2_HW __builtin_amdgcn_exp2f
#define C5LOG2E 7.213475204444817f  // 5 * log2(e)

// prep: 512 blocks x 16 rows, 16-lane-group float4 layout (r11-proven).
__global__ __launch_bounds__(256) void prep_kernel(
    const int* __restrict__ user, const int* __restrict__ pos,
    const float* __restrict__ uw, const float* __restrict__ iw,
    __hip_bfloat16* __restrict__ u_bf, __hip_bfloat16* __restrict__ p_bf,
    float* __restrict__ up_p)
{
  const int tid  = threadIdx.x;
  const int wave = tid >> 6;
  const int lane = tid & 63;
  const int e    = lane & 15;
  const int row  = blockIdx.x * 16 + wave * 4 + (lane >> 4);

  const int uidx = user[row];
  const int pidx = pos[row];
  const float4 uv = *reinterpret_cast<const float4*>(&uw[(size_t)uidx * EMB + e * 4]);
  const float4 pv = *reinterpret_cast<const float4*>(&iw[(size_t)pidx * EMB + e * 4]);

  float us = uv.x*uv.x + uv.y*uv.y + uv.z*uv.z + uv.w*uv.w;
  float ps = pv.x*pv.x + pv.y*pv.y + pv.z*pv.z + pv.w*pv.w;
  #pragma unroll
  for (int off = 1; off < 16; off <<= 1) {
    us += __shfl_xor(us, off);
    ps += __shfl_xor(ps, off);
  }
  const float ur = 1.0f / fmaxf(sqrtf(us), 1e-12f);
  const float pr = 1.0f / fmaxf(sqrtf(ps), 1e-12f);
  const float4 un = make_float4(uv.x*ur, uv.y*ur, uv.z*ur, uv.w*ur);
  const float4 pn = make_float4(pv.x*pr, pv.y*pr, pv.z*pr, pv.w*pr);

  ushort4 ub, pb;
  ub.x = __bfloat16_as_ushort(__float2bfloat16(un.x));
  ub.y = __bfloat16_as_ushort(__float2bfloat16(un.y));
  ub.z = __bfloat16_as_ushort(__float2bfloat16(un.z));
  ub.w = __bfloat16_as_ushort(__float2bfloat16(un.w));
  pb.x = __bfloat16_as_ushort(__float2bfloat16(pn.x));
  pb.y = __bfloat16_as_ushort(__float2bfloat16(pn.y));
  pb.z = __bfloat16_as_ushort(__float2bfloat16(pn.z));
  pb.w = __bfloat16_as_ushort(__float2bfloat16(pn.w));
  *reinterpret_cast<ushort4*>(&u_bf[(size_t)row * EMB + e * 4]) = ub;
  *reinterpret_cast<ushort4*>(&p_bf[(size_t)row * EMB + e * 4]) = pb;

  float ip = un.x*pn.x + un.y*pn.y + un.z*pn.z + un.w*pn.w;
  #pragma unroll
  for (int off = 1; off < 16; off <<= 1) ip += __shfl_xor(ip, off);

  float upv = 0.0f;
  if (e == 0) {
    const float t = ip * C5LOG2E;
    upv = logf(EXP2_HW(t) + EXP2_HW(ip * t));  // log(exp(ip/T)+exp(ip^2/T))
  }
  upv += __shfl_xor(upv, 16);
  upv += __shfl_xor(upv, 32);

  __shared__ float sred[4];
  if (lane == 0) sred[wave] = upv;
  __syncthreads();
  if (tid == 0)
    up_p[blockIdx.x] = (sred[0] + sred[1]) + (sred[2] + sred[3]);
}

// 2048 blocks = 64 row-strips x 32 col-groups x 2 tiles; 64x32 half-steps;
// PURE compute (no fence/atomic tail — r14/r16/r17 proved the last-block-done
// pattern costs 40-170us in serialized fences/atomics). Single-variable test
// vs r15-round's 1024 blocks: the 60-VGPR shape allows 8 waves/SIMD; 2048
// blocks supply exactly that (2048*4/256 CU = 32 waves/CU).
__global__ __launch_bounds__(256) void gemm_kernel(
    const __hip_bfloat16* __restrict__ U, const __hip_bfloat16* __restrict__ P,
    float* __restrict__ dn_p)
{
  const int tid  = threadIdx.x;
  const int blk  = blockIdx.x;
  const int by   = blk >> 5;           // [0,64)
  const int bx0  = (blk & 31) << 1;    // 2 tiles -> 64 col-tiles
  const int wave = tid >> 6;
  const int lane = tid & 63;
  const int r0   = by * 128 + (wave >> 1) * 64;
  const int lrow = lane & 15;
  const int lk   = (lane >> 4) * 8;

  short8 a[4][2];
  #pragma unroll
  for (int i = 0; i < 4; ++i)
    #pragma unroll
    for (int kk = 0; kk < 2; ++kk)
      a[i][kk] = *reinterpret_cast<const short8*>(
          &U[(size_t)(r0 + i * 16 + lrow) * EMB + kk * 32 + lk]);

  float s0 = 0.0f, s1 = 0.0f, s2 = 0.0f, s3 = 0.0f;

  #pragma unroll 1
  for (int s = 0; s < 4; ++s) {
    // step s: tile t = s>>1, half h = s&1 -> 64 rows x 32 cols
    const int c0 = (bx0 + (s >> 1)) * 128 + (wave & 1) * 64 + (s & 1) * 32;

    short8 b[2][2];
    #pragma unroll
    for (int j = 0; j < 2; ++j)
      #pragma unroll
      for (int kk = 0; kk < 2; ++kk)
        b[j][kk] = *reinterpret_cast<const short8*>(
            &P[(size_t)(c0 + j * 16 + lrow) * EMB + kk * 32 + lk]);

    f32x4 acc[4][2] = {};
    #pragma unroll
    for (int i = 0; i < 4; ++i)
      #pragma unroll
      for (int j = 0; j < 2; ++j) {
        acc[i][j] = mfma16x16x32(a[i][0], b[j][0], acc[i][j]);
        acc[i][j] = mfma16x16x32(a[i][1], b[j][1], acc[i][j]);
      }

    // exp(v/T)=2^(v*C); exp(v^2/T)=2^(v*(v*C)); |v|<=~1.
    #pragma unroll
    for (int i = 0; i < 4; ++i)
      #pragma unroll
      for (int j = 0; j < 2; ++j)
        #pragma unroll
        for (int r = 0; r < 4; ++r) {
          const float v  = acc[i][j][r];
          const float tt = v * C5LOG2E;
          if (j) { s2 += EXP2_HW(tt); s3 += EXP2_HW(v * tt); }
          else   { s0 += EXP2_HW(tt); s1 += EXP2_HW(v * tt); }
        }
  }

  float s = (s0 + s1) + (s2 + s3);
  #pragma unroll
  for (int off = 32; off; off >>= 1) s += __shfl_xor(s, off);

  __shared__ float sredf[4];
  if (lane == 0) sredf[wave] = s;
  __syncthreads();
  if (tid == 0)
    dn_p[blk] = (sredf[0] + sredf[1]) + (sredf[2] + sredf[3]);
}

// Single-block finalize: LDS-bitmap dedup + reductions (r15-round proven).
__global__ __launch_bounds__(1024) void finalize_kernel(
    const int* __restrict__ user, const int* __restrict__ pos,
    const float* __restrict__ up_p, const float* __restrict__ dn_p,
    float* __restrict__ out)
{
  const int tid  = threadIdx.x;
  const int wave = tid >> 6;
  const int lane = tid & 63;

  __shared__ unsigned int bitmap[6250];   // 3125 user words + 3125 item words
  for (int i = tid; i < 6250; i += 1024) bitmap[i] = 0u;
  __syncthreads();
  for (int i = tid; i < 8192; i += 1024) {
    const int u = user[i];
    const int p = pos[i];
    atomicOr(&bitmap[u >> 5], 1u << (u & 31));
    atomicOr(&bitmap[3125 + (p >> 5)], 1u << (p & 31));
  }
  __syncthreads();

  int uc = 0, ic = 0;
  for (int i = tid; i < 3125; i += 1024) uc += __popc(bitmap[i]);
  for (int i = tid; i < 3125; i += 1024) ic += __popc(bitmap[3125 + i]);

  float upv = (tid < 512) ? up_p[tid] : 0.0f;
  float dnv = dn_p[tid] + dn_p[tid + 1024];   // 2048 partials

  #pragma unroll
  for (int off = 32; off; off >>= 1) {
    upv += __shfl_xor(upv, off);
    dnv += __shfl_xor(dnv, off);
    uc  += __shfl_xor(uc, off);
    ic  += __shfl_xor(ic, off);
  }

  __shared__ float sf[2][16];
  __shared__ int   si[2][16];
  if (lane == 0) { sf[0][wave] = upv; sf[1][wave] = dnv; si[0][wave] = uc; si[1][wave] = ic; }
  __syncthreads();
  if (tid == 0) {
    float usum = 0.0f, dsum = 0.0f; int nu = 0, ni = 0;
    #pragma unroll
    for (int w = 0; w < 16; ++w) {
      usum += sf[0][w]; dsum += sf[1][w]; nu += si[0][w]; ni += si[1][w];
    }
    out[0] = -(usum / 8192.0f);
    out[1] = logf(dsum / ((float)nu * (float)ni));
  }
}

extern "C" void kernel_launch(void* const* d_in, const int* in_sizes, int n_in,
                              void* d_out, int out_size, void* d_ws, size_t ws_size,
                              hipStream_t stream) {
  const int*   user = (const int*)d_in[0];
  const int*   pos  = (const int*)d_in[1];
  // d_in[2] = negative (unused by the reference loss)
  const float* uw   = (const float*)d_in[3];
  const float* iw   = (const float*)d_in[4];
  float* out = (float*)d_out;

  char* ws = (char*)d_ws;
  __hip_bfloat16* u_bf = (__hip_bfloat16*)(ws);
  __hip_bfloat16* p_bf = (__hip_bfloat16*)(ws + (1u << 20));
  float* up_p = (float*)(ws + (2u << 20));        // 512
  float* dn_p = up_p + 512;                       // 2048

  prep_kernel<<<512, 256, 0, stream>>>(user, pos, uw, iw, u_bf, p_bf, up_p);
  gemm_kernel<<<2048, 256, 0, stream>>>(u_bf, p_bf, dn_p);
  finalize_kernel<<<1, 1024, 0, stream>>>(user, pos, up_p, dn_p, out);
}

// Round 19
// 37.805 us; speedup vs baseline: 5.1593x; 1.1188x over previous
//
#include <hip/hip_runtime.h>
#include <hip/hip_bf16.h>

#define EMB 64

typedef __attribute__((ext_vector_type(8))) short short8;
typedef __attribute__((ext_vector_type(8))) __bf16 bf16x8;
typedef __attribute__((ext_vector_type(4))) float f32x4;
typedef __attribute__((ext_vector_type(2))) float f32x2;

__device__ inline f32x4 mfma16x16x32(short8 a, short8 b, f32x4 c) {
  return __builtin_amdgcn_mfma_f32_16x16x32_bf16(
      __builtin_bit_cast(bf16x8, a), __builtin_bit_cast(bf16x8, b), c, 0, 0, 0);
}

// Raw v_exp_f32 (2^x). OCML exp2f/__expf are multi-instr expansions (r2-r4).
#define EXP2_HW __builtin_amdgcn_exp2f
#define C5LOG2E 7.213475204444817f  // 5 * log2(e)

// prep: 512 blocks x 16 rows, 16-lane-group float4 layout (r11-proven).
__global__ __launch_bounds__(256) void prep_kernel(
    const int* __restrict__ user, const int* __restrict__ pos,
    const float* __restrict__ uw, const float* __restrict__ iw,
    __hip_bfloat16* __restrict__ u_bf, __hip_bfloat16* __restrict__ p_bf,
    float* __restrict__ up_p)
{
  const int tid  = threadIdx.x;
  const int wave = tid >> 6;
  const int lane = tid & 63;
  const int e    = lane & 15;
  const int row  = blockIdx.x * 16 + wave * 4 + (lane >> 4);

  const int uidx = user[row];
  const int pidx = pos[row];
  const float4 uv = *reinterpret_cast<const float4*>(&uw[(size_t)uidx * EMB + e * 4]);
  const float4 pv = *reinterpret_cast<const float4*>(&iw[(size_t)pidx * EMB + e * 4]);

  float us = uv.x*uv.x + uv.y*uv.y + uv.z*uv.z + uv.w*uv.w;
  float ps = pv.x*pv.x + pv.y*pv.y + pv.z*pv.z + pv.w*pv.w;
  #pragma unroll
  for (int off = 1; off < 16; off <<= 1) {
    us += __shfl_xor(us, off);
    ps += __shfl_xor(ps, off);
  }
  const float ur = 1.0f / fmaxf(sqrtf(us), 1e-12f);
  const float pr = 1.0f / fmaxf(sqrtf(ps), 1e-12f);
  const float4 un = make_float4(uv.x*ur, uv.y*ur, uv.z*ur, uv.w*ur);
  const float4 pn = make_float4(pv.x*pr, pv.y*pr, pv.z*pr, pv.w*pr);

  ushort4 ub, pb;
  ub.x = __bfloat16_as_ushort(__float2bfloat16(un.x));
  ub.y = __bfloat16_as_ushort(__float2bfloat16(un.y));
  ub.z = __bfloat16_as_ushort(__float2bfloat16(un.z));
  ub.w = __bfloat16_as_ushort(__float2bfloat16(un.w));
  pb.x = __bfloat16_as_ushort(__float2bfloat16(pn.x));
  pb.y = __bfloat16_as_ushort(__float2bfloat16(pn.y));
  pb.z = __bfloat16_as_ushort(__float2bfloat16(pn.z));
  pb.w = __bfloat16_as_ushort(__float2bfloat16(pn.w));
  *reinterpret_cast<ushort4*>(&u_bf[(size_t)row * EMB + e * 4]) = ub;
  *reinterpret_cast<ushort4*>(&p_bf[(size_t)row * EMB + e * 4]) = pb;

  float ip = un.x*pn.x + un.y*pn.y + un.z*pn.z + un.w*pn.w;
  #pragma unroll
  for (int off = 1; off < 16; off <<= 1) ip += __shfl_xor(ip, off);

  float upv = 0.0f;
  if (e == 0) {
    const float t = ip * C5LOG2E;
    upv = logf(EXP2_HW(t) + EXP2_HW(ip * t));  // log(exp(ip/T)+exp(ip^2/T))
  }
  upv += __shfl_xor(upv, 16);
  upv += __shfl_xor(upv, 32);

  __shared__ float sred[4];
  if (lane == 0) sred[wave] = upv;
  __syncthreads();
  if (tid == 0)
    up_p[blockIdx.x] = (sred[0] + sred[1]) + (sred[2] + sred[3]);
}

// 1024 blocks = 64 row-strips x 16 col-groups x 4 tiles (r15-proven best
// grid: 4 waves/SIMD; r18 proved 8 waves/SIMD supply doesn't help). 64x32
// half-steps. Epilogue in f32x2 packed math: v_pk_mul/v_pk_add do 2 elements
// per 2-cyc instruction, halving the mul/add issue cost. acc f32x4 low/high
// pairs are consecutive VGPRs -> extraction is free.
__global__ __launch_bounds__(256) void gemm_kernel(
    const __hip_bfloat16* __restrict__ U, const __hip_bfloat16* __restrict__ P,
    float* __restrict__ dn_p)
{
  const int tid  = threadIdx.x;
  const int by   = blockIdx.x >> 4;          // [0,64)
  const int bx0  = (blockIdx.x & 15) << 2;   // 4 tiles -> 64 col-tiles
  const int wave = tid >> 6;
  const int lane = tid & 63;
  const int r0   = by * 128 + (wave >> 1) * 64;
  const int lrow = lane & 15;
  const int lk   = (lane >> 4) * 8;

  short8 a[4][2];
  #pragma unroll
  for (int i = 0; i < 4; ++i)
    #pragma unroll
    for (int kk = 0; kk < 2; ++kk)
      a[i][kk] = *reinterpret_cast<const short8*>(
          &U[(size_t)(r0 + i * 16 + lrow) * EMB + kk * 32 + lk]);

  const f32x2 C2 = {C5LOG2E, C5LOG2E};
  f32x2 sa = {0.0f, 0.0f}, sb = {0.0f, 0.0f};
  f32x2 sc = {0.0f, 0.0f}, sd = {0.0f, 0.0f};

  #pragma unroll 1
  for (int s = 0; s < 8; ++s) {
    // step s: tile t = s>>1, half h = s&1 -> 64 rows x 32 cols
    const int c0 = (bx0 + (s >> 1)) * 128 + (wave & 1) * 64 + (s & 1) * 32;

    short8 b[2][2];
    #pragma unroll
    for (int j = 0; j < 2; ++j)
      #pragma unroll
      for (int kk = 0; kk < 2; ++kk)
        b[j][kk] = *reinterpret_cast<const short8*>(
            &P[(size_t)(c0 + j * 16 + lrow) * EMB + kk * 32 + lk]);

    f32x4 acc[4][2] = {};
    #pragma unroll
    for (int i = 0; i < 4; ++i)
      #pragma unroll
      for (int j = 0; j < 2; ++j) {
        acc[i][j] = mfma16x16x32(a[i][0], b[j][0], acc[i][j]);
        acc[i][j] = mfma16x16x32(a[i][1], b[j][1], acc[i][j]);
      }

    // exp(v/T)=2^(v*C); exp(v^2/T)=2^(v*(v*C)); |v|<=~1. Packed f32 pairs.
    #pragma unroll
    for (int i = 0; i < 4; ++i)
      #pragma unroll
      for (int j = 0; j < 2; ++j) {
        const f32x2 vlo = {acc[i][j][0], acc[i][j][1]};
        const f32x2 vhi = {acc[i][j][2], acc[i][j][3]};
        const f32x2 tlo = vlo * C2;          // v_pk_mul_f32
        const f32x2 thi = vhi * C2;
        const f32x2 qlo = vlo * tlo;         // v_pk_mul_f32
        const f32x2 qhi = vhi * thi;
        const f32x2 e0 = {EXP2_HW(tlo[0]), EXP2_HW(tlo[1])};
        const f32x2 e1 = {EXP2_HW(thi[0]), EXP2_HW(thi[1])};
        const f32x2 e2 = {EXP2_HW(qlo[0]), EXP2_HW(qlo[1])};
        const f32x2 e3 = {EXP2_HW(qhi[0]), EXP2_HW(qhi[1])};
        sa += e0;                            // v_pk_add_f32
        sb += e1;
        sc += e2;
        sd += e3;
      }
  }

  float s = ((sa[0] + sa[1]) + (sb[0] + sb[1])) +
            ((sc[0] + sc[1]) + (sd[0] + sd[1]));
  #pragma unroll
  for (int off = 32; off; off >>= 1) s += __shfl_xor(s, off);

  __shared__ float sredf[4];
  if (lane == 0) sredf[wave] = s;
  __syncthreads();
  if (tid == 0)
    dn_p[blockIdx.x] = (sredf[0] + sredf[1]) + (sredf[2] + sredf[3]);
}

// Single-block finalize: LDS-bitmap dedup + reductions (r15-proven).
__global__ __launch_bounds__(1024) void finalize_kernel(
    const int* __restrict__ user, const int* __restrict__ pos,
    const float* __restrict__ up_p, const float* __restrict__ dn_p,
    float* __restrict__ out)
{
  const int tid  = threadIdx.x;
  const int wave = tid >> 6;
  const int lane = tid & 63;

  __shared__ unsigned int bitmap[6250];   // 3125 user words + 3125 item words
  for (int i = tid; i < 6250; i += 1024) bitmap[i] = 0u;
  __syncthreads();
  for (int i = tid; i < 8192; i += 1024) {
    const int u = user[i];
    const int p = pos[i];
    atomicOr(&bitmap[u >> 5], 1u << (u & 31));
    atomicOr(&bitmap[3125 + (p >> 5)], 1u << (p & 31));
  }
  __syncthreads();

  int uc = 0, ic = 0;
  for (int i = tid; i < 3125; i += 1024) uc += __popc(bitmap[i]);
  for (int i = tid; i < 3125; i += 1024) ic += __popc(bitmap[3125 + i]);

  float upv = (tid < 512) ? up_p[tid] : 0.0f;
  float dnv = dn_p[tid];                  // exactly 1024 partials

  #pragma unroll
  for (int off = 32; off; off >>= 1) {
    upv += __shfl_xor(upv, off);
    dnv += __shfl_xor(dnv, off);
    uc  += __shfl_xor(uc, off);
    ic  += __shfl_xor(ic, off);
  }

  __shared__ float sf[2][16];
  __shared__ int   si[2][16];
  if (lane == 0) { sf[0][wave] = upv; sf[1][wave] = dnv; si[0][wave] = uc; si[1][wave] = ic; }
  __syncthreads();
  if (tid == 0) {
    float usum = 0.0f, dsum = 0.0f; int nu = 0, ni = 0;
    #pragma unroll
    for (int w = 0; w < 16; ++w) {
      usum += sf[0][w]; dsum += sf[1][w]; nu += si[0][w]; ni += si[1][w];
    }
    out[0] = -(usum / 8192.0f);
    out[1] = logf(dsum / ((float)nu * (float)ni));
  }
}

extern "C" void kernel_launch(void* const* d_in, const int* in_sizes, int n_in,
                              void* d_out, int out_size, void* d_ws, size_t ws_size,
                              hipStream_t stream) {
  const int*   user = (const int*)d_in[0];
  const int*   pos  = (const int*)d_in[1];
  // d_in[2] = negative (unused by the reference loss)
  const float* uw   = (const float*)d_in[3];
  const float* iw   = (const float*)d_in[4];
  float* out = (float*)d_out;

  char* ws = (char*)d_ws;
  __hip_bfloat16* u_bf = (__hip_bfloat16*)(ws);
  __hip_bfloat16* p_bf = (__hip_bfloat16*)(ws + (1u << 20));
  float* up_p = (float*)(ws + (2u << 20));        // 512
  float* dn_p = up_p + 512;                       // 1024

  prep_kernel<<<512, 256, 0, stream>>>(user, pos, uw, iw, u_bf, p_bf, up_p);
  gemm_kernel<<<1024, 256, 0, stream>>>(u_bf, p_bf, dn_p);
  finalize_kernel<<<1, 1024, 0, stream>>>(user, pos, up_p, dn_p, out);
}